// Round 6
// baseline (191.487 us; speedup 1.0000x reference)
//
#include <hip/hip_runtime.h>
#include <cstdint>
#include <cstddef>

// Problem constants (fixed by setup_inputs)
#define N_ROWS 2048
#define DIM    512
#define QN     3
#define KQ     8192
#define NCOL   (QN * KQ)   // 24576
#define NCLASS 16

// 8-phase 256x256 fp8 GEMM geometry
#define BM 256
#define BN 256
#define BKT 64              // K-tile depth (fp8: 64 B row slabs)
#define NT  (DIM / BKT)     // 8 K-tiles
#define NBLKP (NCOL / BN)   // 96 column blocks

typedef __attribute__((ext_vector_type(4))) float f32x4;

// ---------------------------------------------------------------------------
// Kernel 1: L2-normalize rows of x and q_data, scale by 16, cast to fp8
// e4m3 (OCP). One wave per row; 4 rows per 256-thread block.
// Scale 16: unit-norm 512-d rows have elem sigma ~0.044 -> x16 clears
// e4m3's 2^-6 subnormal cliff. GEMM result = 256*sim.
// ROUND-11 GLOBAL HALF-SWAP: keyed on row BIT 2 now (64-B slabs -> the
// half-XOR bit of the new LDS swizzle is row bit2, was bit3 for 128-B
// slabs). Rows with bit2 set store each 16-B chunk's two 8-B halves
// swapped, baking the swizzle's half-bit into global memory so
// global_load_lds (which cannot permute within a 16-B load) still works.
// Also zeroes out[0] (replaces the hipMemsetAsync dispatch).
// ---------------------------------------------------------------------------
__global__ __launch_bounds__(256) void norm_cast_kernel(
    const float* __restrict__ x, const float* __restrict__ q,
    unsigned char* __restrict__ xb, unsigned char* __restrict__ qb,
    float* __restrict__ out) {
    if (blockIdx.x == 0 && threadIdx.x == 0) out[0] = 0.f;
    int row = blockIdx.x * 4 + (threadIdx.x >> 6);
    int lane = threadIdx.x & 63;
    const float* src;
    unsigned char* dst;
    if (row < N_ROWS) {
        src = x + (size_t)row * DIM;
        dst = xb + (size_t)row * DIM;
    } else {
        src = q + (size_t)(row - N_ROWS) * DIM;
        dst = qb + (size_t)(row - N_ROWS) * DIM;
    }
    float4 v0 = ((const float4*)src)[lane * 2];
    float4 v1 = ((const float4*)src)[lane * 2 + 1];
    float ss = v0.x*v0.x + v0.y*v0.y + v0.z*v0.z + v0.w*v0.w
             + v1.x*v1.x + v1.y*v1.y + v1.z*v1.z + v1.w*v1.w;
    #pragma unroll
    for (int off = 1; off < 64; off <<= 1)
        ss += __shfl_xor(ss, off, 64);
    float inv = 16.0f / fmaxf(sqrtf(ss), 1e-12f);
    int w0 = __builtin_amdgcn_cvt_pk_fp8_f32(v0.x * inv, v0.y * inv, 0,  false);
    w0     = __builtin_amdgcn_cvt_pk_fp8_f32(v0.z * inv, v0.w * inv, w0, true);
    int w1 = __builtin_amdgcn_cvt_pk_fp8_f32(v1.x * inv, v1.y * inv, 0,  false);
    w1     = __builtin_amdgcn_cvt_pk_fp8_f32(v1.z * inv, v1.w * inv, w1, true);
    uint2 o; o.x = (unsigned)w0; o.y = (unsigned)w1;
    // half-swap bake: lane's 8 B go to (lane*8) ^ (row.bit2 * 8)
    int r2 = (row >> 2) & 1;
    *(uint2*)(dst + ((lane * 8) ^ (r2 << 3))) = o;
}

// ---------------------------------------------------------------------------
// Kernel 2: fp8 MFMA GEMM (M=2048, N=24576, K=512), result = 256*sim.
// ROUND-11: 8-phase 256x256 counted-vmcnt schedule (the T3+T4+T5 template,
// the only structure measured past the 2-barrier ~900 TF ceiling), fp8-
// adapted with BK=64 so byte geometry == template's bf16 BK=64:
//   - 512 thr / 8 waves (2M x 4N), per-wave output 128x64, acc[8][4].
//   - LDS 64 KB static: 2 dbuf x (A 16 KB + B 16 KB), 256 rows x 64 B.
//   - 8 K-tiles; 4 iters x 8 phases. Each phase: 12 ds_read_b64 (one
//     C-quadrant's frags) + 1 global_load_lds half-tile prefetch +
//     [vmcnt(3) at phases 4/8 only] + raw s_barrier + setprio(1) +
//     16 MFMA + setprio(0) + s_barrier. NO __syncthreads in the loop
//     (it would emit the vmcnt(0) drain this schedule exists to avoid).
//   - Prologue stages 7 half-tiles, vmcnt(3): steady state keeps 3
//     half-tiles in flight across barriers. Tail: vmcnt(0) at iter3
//     phase 4 (protects tile 7's last half, staged at iter3 phase 1).
// 64-B-slab swizzle (re-derived for BKT=64): element (r,k) at byte
//     r*64 + (((k>>4) ^ (r&3))<<4) + ((((k>>3)&1) ^ ((r>>2)&1))<<3) + (k&7)
//   Half-bit pre-baked into GLOBAL layout by norm_cast (bit2 key);
//   slot-XOR pre-baked into the staging source segment (stC). Bank
//   census of the b64 fragment reads: uniform 4 accesses/bank = the
//   inherent wave64-b64 minimum -> conflict-free.
// Epilogue: exp + mask + quad shfl-reduce + unique-slot LDS reduce +
// one coalesced 256-float store into P (atomic-T removed: round-5 showed
// cross-XCD atomic ping-pong on 8 KB costs ~8 us).
// ---------------------------------------------------------------------------
#define MF(A_, B_, C_) C_ = __builtin_amdgcn_mfma_f32_16x16x32_fp8_fp8(A_, B_, C_, 0, 0, 0)

#define STAGE(h_) do {                                                          \
    const int t_ = (h_) >> 2, bf_ = t_ & 1, ht_ = (h_) & 3;                     \
    const int chunk_ = (ht_ & 1) * 8 + wave;   /* 8 KB half: 8 chunks */        \
    const int R_ = chunk_ * 16 + stR;          /* tile row 0..255 */            \
    const int k0_ = t_ * BKT;                                                   \
    if (ht_ < 2) {                                                              \
        __builtin_amdgcn_global_load_lds(                                       \
            (const __attribute__((address_space(1))) unsigned int*)             \
                (Xb + (size_t)(m0 + R_) * DIM + k0_ + stC),                     \
            (__attribute__((address_space(3))) unsigned int*)                   \
                &As[bf_][chunk_ * 1024 + lane * 16], 16, 0, 0);                 \
    } else {                                                                    \
        __builtin_amdgcn_global_load_lds(                                       \
            (const __attribute__((address_space(1))) unsigned int*)             \
                (Qb + (size_t)(n0 + R_) * DIM + k0_ + stC),                     \
            (__attribute__((address_space(3))) unsigned int*)                   \
                &Bs[bf_][chunk_ * 1024 + lane * 16], 16, 0, 0);                 \
    }                                                                           \
} while (0)

__global__ __launch_bounds__(512) void gemm_epilogue_kernel(
    const unsigned char* __restrict__ Xb,   // [2048][512] fp8 (half-baked)
    const unsigned char* __restrict__ Qb,   // [24576][512] fp8 (half-baked)
    const int* __restrict__ targets,
    const int* __restrict__ q_targets,
    const int* __restrict__ order_p,
    float* __restrict__ P) {                 // [NBLKP][N_ROWS] partial sums

    __shared__ unsigned char As[2][BM * BKT];   // 32 KB
    __shared__ unsigned char Bs[2][BN * BKT];   // 32 KB

    const int tid  = threadIdx.x;
    const int lane = tid & 63;
    const int wave = tid >> 6;               // 0..7
    const int wm = wave >> 2, wn = wave & 3; // 2M x 4N wave grid
    const int quad = lane >> 4;              // 0..3
    const int l15  = lane & 15;
    const int r3l  = l15 & 3;                // row mod 4 (slot-XOR key)
    const int r2l  = (l15 >> 2) & 1;         // row bit2 (half-XOR key)

    // XCD-aware decode: 768 blocks, 8 rowb x 96 colb; same-XCD blocks
    // share a B-panel (consecutive rowb per colb).
    const int b    = blockIdx.x;             // 0..767
    const int xcd  = b & 7;
    const int g    = b >> 3;                 // 0..95
    const int colb = (g >> 3) * 8 + xcd;     // 0..95
    const int rowb = g & 7;                  // 0..7
    const int m0 = rowb * BM;
    const int n0 = colb * BN;

    f32x4 acc[8][4];
    #pragma unroll
    for (int i = 0; i < 8; i++)
        #pragma unroll
        for (int j = 0; j < 4; j++)
            acc[i][j] = (f32x4){0.f, 0.f, 0.f, 0.f};

    // Staging: 1-KB chunk = 16 rows x 64 B. Lane l -> row chunk*16+(l>>2),
    // global 16-B seg ((l&3) ^ (row&3)) (inverse of read-side slot-XOR;
    // the half-bit lives in the global layout).
    const int stR = lane >> 2;                       // 0..15
    const int stC = ((lane & 3) ^ (stR & 3)) * 16;   // byte off in 64-B slab

    // Loop-invariant fragment-read offsets (ks = 0 and 32):
    //   logical slot s = (ks>>4) + (quad>>1), half h = quad&1
    //   phys = ((s ^ (r&3))<<4) + ((h ^ r.bit2)<<3)
    const int swh = ((quad & 1) ^ r2l) << 3;
    const int sw0 = ((((quad >> 1)    ) ^ r3l) << 4) + swh; // ks=0
    const int sw1 = ((((quad >> 1) + 2) ^ r3l) << 4) + swh; // ks=32

    // ---- Prologue: stage 7 half-tiles (tile0 complete + tile1 A+Bh0) ----
    #pragma unroll
    for (int h = 0; h < 7; ++h) STAGE(h);
    asm volatile("s_waitcnt vmcnt(3)" ::: "memory");   // tile 0 landed
    __builtin_amdgcn_s_barrier();

    // ---- Main: 4 iters x 8 phases, fully unrolled ----
    #pragma unroll
    for (int ph = 0; ph < 32; ++ph) {
        const int it = ph >> 3, p = ph & 7;
        const int tt = it * 2 + (p >> 2);       // tile for this phase
        const int q  = p & 3;                   // C-quadrant
        const int bf = tt & 1;
        const unsigned char* Ab = &As[bf][0];
        const unsigned char* Bb = &Bs[bf][0];
        const int mt0 = (q >> 1) * 4, ntb = (q & 1) * 2;

        long a0[2], a1[2], a2[2], a3[2], b0[2], b1[2];
        {
            const unsigned char* pA0 = Ab + (wm * 128 + (mt0 + 0) * 16 + l15) * BKT;
            const unsigned char* pA1 = Ab + (wm * 128 + (mt0 + 1) * 16 + l15) * BKT;
            const unsigned char* pA2 = Ab + (wm * 128 + (mt0 + 2) * 16 + l15) * BKT;
            const unsigned char* pA3 = Ab + (wm * 128 + (mt0 + 3) * 16 + l15) * BKT;
            a0[0] = *(const long*)(pA0 + sw0); a0[1] = *(const long*)(pA0 + sw1);
            a1[0] = *(const long*)(pA1 + sw0); a1[1] = *(const long*)(pA1 + sw1);
            a2[0] = *(const long*)(pA2 + sw0); a2[1] = *(const long*)(pA2 + sw1);
            a3[0] = *(const long*)(pA3 + sw0); a3[1] = *(const long*)(pA3 + sw1);
            const unsigned char* pB0 = Bb + (wn * 64 + (ntb + 0) * 16 + l15) * BKT;
            const unsigned char* pB1 = Bb + (wn * 64 + (ntb + 1) * 16 + l15) * BKT;
            b0[0] = *(const long*)(pB0 + sw0); b0[1] = *(const long*)(pB0 + sw1);
            b1[0] = *(const long*)(pB1 + sw0); b1[1] = *(const long*)(pB1 + sw1);
        }

        const int hs = 7 + ph;                  // stage stream, 1/phase
        if (hs < 4 * NT) STAGE(hs);

        if (q == 3) {                            // phases 4 and 8 only
            if (it == 3) asm volatile("s_waitcnt vmcnt(0)" ::: "memory");
            else         asm volatile("s_waitcnt vmcnt(3)" ::: "memory");
        }
        __builtin_amdgcn_s_barrier();

        __builtin_amdgcn_s_setprio(1);
        #pragma unroll
        for (int ks = 0; ks < 2; ++ks) {
            MF(a0[ks], b0[ks], acc[mt0 + 0][ntb + 0]);
            MF(a0[ks], b1[ks], acc[mt0 + 0][ntb + 1]);
            MF(a1[ks], b0[ks], acc[mt0 + 1][ntb + 0]);
            MF(a1[ks], b1[ks], acc[mt0 + 1][ntb + 1]);
            MF(a2[ks], b0[ks], acc[mt0 + 2][ntb + 0]);
            MF(a2[ks], b1[ks], acc[mt0 + 2][ntb + 1]);
            MF(a3[ks], b0[ks], acc[mt0 + 3][ntb + 0]);
            MF(a3[ks], b1[ks], acc[mt0 + 3][ntb + 1]);
        }
        __builtin_amdgcn_s_setprio(0);
        __builtin_amdgcn_s_barrier();
    }

    // ---- Epilogue: exp + mask + quad-reduce + LDS reduce + P store ----
    __syncthreads();                     // vmcnt==0 here; fence LDS reuse
    float* red = (float*)&As[0][0];      // [4 wn][256 rows], 4 KB

    const int ord  = order_p[0];
    const int qIdx = colb / (KQ / BN);   // 32 col-blocks per queue
    const bool isOrd = (qIdx == ord);
    const int kbase = n0 - qIdx * KQ;

    int qtv[4] = {0, 0, 0, 0};
    if (isOrd) {
        #pragma unroll
        for (int nt = 0; nt < 4; nt++)
            qtv[nt] = q_targets[ord * KQ + kbase + wn * 64 + nt * 16 + l15];
    }

    #pragma unroll
    for (int mt = 0; mt < 8; mt++) {
        int rowl = wm * 128 + mt * 16 + quad * 4;       // local row base
        int tg[4] = {0, 0, 0, 0};
        if (isOrd) {
            #pragma unroll
            for (int reg = 0; reg < 4; reg++) tg[reg] = targets[m0 + rowl + reg];
        }
        #pragma unroll
        for (int reg = 0; reg < 4; reg++) {
            float s = 0.f;
            #pragma unroll
            for (int nt = 0; nt < 4; nt++) {
                float v256 = acc[mt][nt][reg];          // 256 * sim
                float e = __expf(v256 * 0.015625f - 4.0f); // exp(4*sim-4)
                if (isOrd && tg[reg] == qtv[nt]) e = 0.f;
                s += e;
            }
            s += __shfl_xor(s, 1, 64);
            s += __shfl_xor(s, 2, 64);
            s += __shfl_xor(s, 4, 64);
            s += __shfl_xor(s, 8, 64);
            if (l15 == 0)
                red[wn * 256 + rowl + reg] = s;   // unique slot per wave
        }
    }
    __syncthreads();
    if (tid < 256)
        P[(size_t)colb * N_ROWS + m0 + tid] =
            red[tid] + red[256 + tid] + red[512 + tid] + red[768 + tid];
}

// ---------------------------------------------------------------------------
// Kernel 3: per-row total = sum over 96 partials (coalesced), count via
// per-wave ballot histogram, then accumulate mean(log(total/cnt)) into
// out (zeroed by norm_cast earlier in the stream).
// ---------------------------------------------------------------------------
__global__ __launch_bounds__(256) void reduce_kernel(
    const float* __restrict__ P,
    const int* __restrict__ targets,
    const int* __restrict__ q_targets,
    const int* __restrict__ order_p,
    float* __restrict__ out) {
    __shared__ int hist[NCLASS];
    __shared__ float partial[4];
    int tid = threadIdx.x;
    int wave = tid >> 6, lane = tid & 63;
    if (tid < NCLASS) hist[tid] = 0;
    __syncthreads();
    int ord = order_p[0];

    int local[NCLASS];
    #pragma unroll
    for (int c = 0; c < NCLASS; c++) local[c] = 0;
    for (int i = tid; i < KQ; i += 256) {           // 32 iterations
        int v = q_targets[ord * KQ + i];
        #pragma unroll
        for (int c = 0; c < NCLASS; c++)
            local[c] += __popcll(__ballot(v == c)); // wave-uniform count
    }
    if (lane == 0) {
        #pragma unroll
        for (int c = 0; c < NCLASS; c++)
            atomicAdd(&hist[c], local[c]);
    }
    __syncthreads();

    int r = blockIdx.x * 256 + tid;      // 8 blocks x 256 = 2048 rows
    float total = 0.f;
    #pragma unroll 8
    for (int nb = 0; nb < NBLKP; nb++)
        total += P[(size_t)nb * N_ROWS + r];   // coalesced across threads
    float cnt = (float)(QN * KQ - hist[targets[r]]);
    float v = logf(total / cnt);

    #pragma unroll
    for (int off = 1; off < 64; off <<= 1)
        v += __shfl_xor(v, off, 64);
    if (lane == 0) partial[wave] = v;
    __syncthreads();
    if (tid == 0)
        atomicAdd(out, (partial[0] + partial[1] + partial[2] + partial[3])
                       * (1.0f / (float)N_ROWS));
}

// ---------------------------------------------------------------------------
extern "C" void kernel_launch(void* const* d_in, const int* in_sizes, int n_in,
                              void* d_out, int out_size, void* d_ws, size_t ws_size,
                              hipStream_t stream) {
    const float* x         = (const float*)d_in[0];
    const float* q         = (const float*)d_in[1];
    const int*   targets   = (const int*)d_in[2];
    const int*   q_targets = (const int*)d_in[3];
    const int*   order     = (const int*)d_in[4];
    float* out = (float*)d_out;

    // Workspace: P (96*2048 f32 = 768 KB) | Xb (1 MB fp8) | Qb (12 MB fp8)
    char* ws = (char*)d_ws;
    float* P = (float*)ws;
    unsigned char* Xb = (unsigned char*)(ws + (size_t)NBLKP * N_ROWS * 4);
    unsigned char* Qb = Xb + (size_t)N_ROWS * DIM;

    norm_cast_kernel<<<(N_ROWS + NCOL) / 4, 256, 0, stream>>>(x, q, Xb, Qb, out);

    gemm_epilogue_kernel<<<NBLKP * (N_ROWS / BM), 512, 0, stream>>>(
        Xb, Qb, targets, q_targets, order, P);

    reduce_kernel<<<N_ROWS / 256, 256, 0, stream>>>(P, targets, q_targets, order, out);
}

// Round 7
// 180.505 us; speedup vs baseline: 1.0608x; 1.0608x over previous
//
#include <hip/hip_runtime.h>
#include <cstdint>
#include <cstddef>

// Problem constants (fixed by setup_inputs)
#define N_ROWS 2048
#define DIM    512
#define QN     3
#define KQ     8192
#define NCOL   (QN * KQ)   // 24576
#define NCLASS 16

// 8-phase 256x256 fp8 GEMM geometry
#define BM 256
#define BN 256
#define BKT 64              // K-tile depth (fp8: 64 B row slabs)
#define NT  (DIM / BKT)     // 8 K-tiles
#define NBLKP (NCOL / BN)   // 96 column blocks

typedef __attribute__((ext_vector_type(4))) float f32x4;

// ---------------------------------------------------------------------------
// Kernel 1: L2-normalize rows of x and q_data, scale by 16, cast to fp8
// e4m3 (OCP). One wave per row; 4 rows per 256-thread block.
// GLOBAL HALF-SWAP keyed on row bit2 (64-B slabs): rows with bit2 set
// store each 16-B chunk's two 8-B halves swapped, baking the LDS swizzle's
// half-bit into global memory so global_load_lds (which cannot permute
// within a 16-B load) still works.  (Slot-level swizzle is baked into the
// staging source segment, not here.)  Zeroes out[0].
// ---------------------------------------------------------------------------
__global__ __launch_bounds__(256) void norm_cast_kernel(
    const float* __restrict__ x, const float* __restrict__ q,
    unsigned char* __restrict__ xb, unsigned char* __restrict__ qb,
    float* __restrict__ out) {
    if (blockIdx.x == 0 && threadIdx.x == 0) out[0] = 0.f;
    int row = blockIdx.x * 4 + (threadIdx.x >> 6);
    int lane = threadIdx.x & 63;
    const float* src;
    unsigned char* dst;
    if (row < N_ROWS) {
        src = x + (size_t)row * DIM;
        dst = xb + (size_t)row * DIM;
    } else {
        src = q + (size_t)(row - N_ROWS) * DIM;
        dst = qb + (size_t)(row - N_ROWS) * DIM;
    }
    float4 v0 = ((const float4*)src)[lane * 2];
    float4 v1 = ((const float4*)src)[lane * 2 + 1];
    float ss = v0.x*v0.x + v0.y*v0.y + v0.z*v0.z + v0.w*v0.w
             + v1.x*v1.x + v1.y*v1.y + v1.z*v1.z + v1.w*v1.w;
    #pragma unroll
    for (int off = 1; off < 64; off <<= 1)
        ss += __shfl_xor(ss, off, 64);
    float inv = 16.0f / fmaxf(sqrtf(ss), 1e-12f);
    int w0 = __builtin_amdgcn_cvt_pk_fp8_f32(v0.x * inv, v0.y * inv, 0,  false);
    w0     = __builtin_amdgcn_cvt_pk_fp8_f32(v0.z * inv, v0.w * inv, w0, true);
    int w1 = __builtin_amdgcn_cvt_pk_fp8_f32(v1.x * inv, v1.y * inv, 0,  false);
    w1     = __builtin_amdgcn_cvt_pk_fp8_f32(v1.z * inv, v1.w * inv, w1, true);
    uint2 o; o.x = (unsigned)w0; o.y = (unsigned)w1;
    // half-swap bake: lane's 8 B go to (lane*8) ^ (row.bit2 * 8)
    int r2 = (row >> 2) & 1;
    *(uint2*)(dst + ((lane * 8) ^ (r2 << 3))) = o;
}

// ---------------------------------------------------------------------------
// Kernel 2: fp8 MFMA GEMM (M=2048, N=24576, K=512), result = 256*sim.
// 8-phase 256x256 counted-vmcnt schedule (T3+T4+T5 template).
// ROUND-12 FIXES (round-11 post-mortem: 85us, MfmaUtil 23%, 12.6M
// conflicts = drain-per-phase signature + 2-way quad conflicts):
//  (1) ALIAS-SPLIT BUFFERS: As0/As1/Bs0/Bs1 are four DISTINCT __shared__
//      objects.  Buffer choice folds to a specific object under the full
//      unroll, so LLVM can prove each phase's ds_reads are independent of
//      the in-flight global_load_lds writes to the OTHER buffer -> no
//      compiler-inserted vmcnt drains killing the counted-vmcnt pipeline.
//  (2) BANK-COMPLETE SWIZZLE: element (r,k) at byte
//        r*64 + ((slot ^ (2*r.b1 + r.b3))<<4) + ((half ^ r.b2)<<3) + (k&7)
//      slot key (b1,b3), half key b2: (b0, slot_phys, half_phys) is a
//      bijection of (b0,b1,b2,b3) -> each quad's 16 b64 lanes cover all
//      32 banks exactly once (round-11 key (b1,b0) ignored b3 -> 2-way).
//  (3) sched_barrier(0) after each waitcnt asm (rule #18).
// Schedule (unchanged, template-inherited): 512 thr / 8 waves (2M x 4N),
// acc[8][4]; 8 K-tiles, 4 iters x 8 phases; per phase 12 ds_read_b64 +
// 1 global_load_lds half-tile + [vmcnt(3) at phases 4/8] + raw s_barrier
// + setprio(1) + 16 MFMA + setprio(0) + s_barrier.  Prologue 7 halves,
// vmcnt(3); tail vmcnt(0) at iter3 phase 4.  No __syncthreads in loop.
// Epilogue: exp + mask + quad shfl-reduce + unique-slot LDS reduce +
// coalesced 256-float store into P.
// ---------------------------------------------------------------------------
#define MF(A_, B_, C_) C_ = __builtin_amdgcn_mfma_f32_16x16x32_fp8_fp8(A_, B_, C_, 0, 0, 0)

#define STAGE(h_) do {                                                          \
    const int t_ = (h_) >> 2, ht_ = (h_) & 3;                                   \
    const int chunk_ = (ht_ & 1) * 8 + wave;   /* 8 KB half: 8 chunks */        \
    const int R_ = chunk_ * 16 + stR;          /* tile row 0..255 */            \
    const int k0_ = t_ * BKT;                                                   \
    if (ht_ < 2) {                                                              \
        unsigned char* d_ = ((t_ & 1) ? As1 : As0) + chunk_ * 1024 + lane * 16; \
        __builtin_amdgcn_global_load_lds(                                       \
            (const __attribute__((address_space(1))) unsigned int*)             \
                (Xb + (size_t)(m0 + R_) * DIM + k0_ + stC),                     \
            (__attribute__((address_space(3))) unsigned int*)d_, 16, 0, 0);     \
    } else {                                                                    \
        unsigned char* d_ = ((t_ & 1) ? Bs1 : Bs0) + chunk_ * 1024 + lane * 16; \
        __builtin_amdgcn_global_load_lds(                                       \
            (const __attribute__((address_space(1))) unsigned int*)             \
                (Qb + (size_t)(n0 + R_) * DIM + k0_ + stC),                     \
            (__attribute__((address_space(3))) unsigned int*)d_, 16, 0, 0);     \
    }                                                                           \
} while (0)

__global__ __launch_bounds__(512) void gemm_epilogue_kernel(
    const unsigned char* __restrict__ Xb,   // [2048][512] fp8 (half-baked)
    const unsigned char* __restrict__ Qb,   // [24576][512] fp8 (half-baked)
    const int* __restrict__ targets,
    const int* __restrict__ q_targets,
    const int* __restrict__ order_p,
    float* __restrict__ P) {                 // [NBLKP][N_ROWS] partial sums

    __shared__ unsigned char As0[BM * BKT];  // 16 KB each, 64 KB total
    __shared__ unsigned char As1[BM * BKT];
    __shared__ unsigned char Bs0[BN * BKT];
    __shared__ unsigned char Bs1[BN * BKT];

    const int tid  = threadIdx.x;
    const int lane = tid & 63;
    const int wave = tid >> 6;               // 0..7
    const int wm = wave >> 2, wn = wave & 3; // 2M x 4N wave grid
    const int quad = lane >> 4;              // 0..3
    const int l15  = lane & 15;
    const int r2l  = (l15 >> 2) & 1;         // row bit2 (half-XOR key)
    const int skey = ((l15 >> 1) & 1) * 2 + ((l15 >> 3) & 1); // slot key (b1,b3)

    // XCD-aware decode: 768 blocks, 8 rowb x 96 colb.
    const int b    = blockIdx.x;             // 0..767
    const int xcd  = b & 7;
    const int g    = b >> 3;                 // 0..95
    const int colb = (g >> 3) * 8 + xcd;     // 0..95
    const int rowb = g & 7;                  // 0..7
    const int m0 = rowb * BM;
    const int n0 = colb * BN;

    f32x4 acc[8][4];
    #pragma unroll
    for (int i = 0; i < 8; i++)
        #pragma unroll
        for (int j = 0; j < 4; j++)
            acc[i][j] = (f32x4){0.f, 0.f, 0.f, 0.f};

    // Staging: 1-KB chunk = 16 rows x 64 B. Lane l -> row chunk*16+(l>>2),
    // global 16-B seg (l&3) ^ slot_key(row) (inverse of read-side slot
    // XOR; the half-bit lives in the global layout).
    const int stR = lane >> 2;                       // 0..15
    const int stC = ((lane & 3) ^ (((stR >> 1) & 1) * 2 + ((stR >> 3) & 1))) * 16;

    // Loop-invariant fragment-read offsets (ks = 0 and 32):
    //   logical slot s = (ks>>4) + (quad>>1), half h = quad&1
    //   phys = ((s ^ skey)<<4) + ((h ^ b2)<<3)
    const int swh = ((quad & 1) ^ r2l) << 3;
    const int sw0 = ((((quad >> 1)    ) ^ skey) << 4) + swh; // ks=0
    const int sw1 = ((((quad >> 1) + 2) ^ skey) << 4) + swh; // ks=32

    // ---- Prologue: stage 7 half-tiles (tile0 complete + tile1 A+Bh0) ----
    #pragma unroll
    for (int h = 0; h < 7; ++h) STAGE(h);
    asm volatile("s_waitcnt vmcnt(3)" ::: "memory");   // tile 0 landed
    __builtin_amdgcn_sched_barrier(0);
    __builtin_amdgcn_s_barrier();

    // ---- Main: 4 iters x 8 phases, fully unrolled ----
    #pragma unroll
    for (int ph = 0; ph < 32; ++ph) {
        const int it = ph >> 3, p = ph & 7;
        const int tt = it * 2 + (p >> 2);       // tile for this phase
        const int q  = p & 3;                   // C-quadrant
        const unsigned char* Ab = (tt & 1) ? As1 : As0;
        const unsigned char* Bb = (tt & 1) ? Bs1 : Bs0;
        const int mt0 = (q >> 1) * 4, ntb = (q & 1) * 2;

        long a0[2], a1[2], a2[2], a3[2], b0[2], b1[2];
        {
            const unsigned char* pA0 = Ab + (wm * 128 + (mt0 + 0) * 16 + l15) * BKT;
            const unsigned char* pA1 = Ab + (wm * 128 + (mt0 + 1) * 16 + l15) * BKT;
            const unsigned char* pA2 = Ab + (wm * 128 + (mt0 + 2) * 16 + l15) * BKT;
            const unsigned char* pA3 = Ab + (wm * 128 + (mt0 + 3) * 16 + l15) * BKT;
            a0[0] = *(const long*)(pA0 + sw0); a0[1] = *(const long*)(pA0 + sw1);
            a1[0] = *(const long*)(pA1 + sw0); a1[1] = *(const long*)(pA1 + sw1);
            a2[0] = *(const long*)(pA2 + sw0); a2[1] = *(const long*)(pA2 + sw1);
            a3[0] = *(const long*)(pA3 + sw0); a3[1] = *(const long*)(pA3 + sw1);
            const unsigned char* pB0 = Bb + (wn * 64 + (ntb + 0) * 16 + l15) * BKT;
            const unsigned char* pB1 = Bb + (wn * 64 + (ntb + 1) * 16 + l15) * BKT;
            b0[0] = *(const long*)(pB0 + sw0); b0[1] = *(const long*)(pB0 + sw1);
            b1[0] = *(const long*)(pB1 + sw0); b1[1] = *(const long*)(pB1 + sw1);
        }

        const int hs = 7 + ph;                  // stage stream, 1/phase
        if (hs < 4 * NT) STAGE(hs);

        if (q == 3) {                            // phases 4 and 8 only
            if (it == 3) asm volatile("s_waitcnt vmcnt(0)" ::: "memory");
            else         asm volatile("s_waitcnt vmcnt(3)" ::: "memory");
            __builtin_amdgcn_sched_barrier(0);
        }
        __builtin_amdgcn_s_barrier();

        __builtin_amdgcn_s_setprio(1);
        #pragma unroll
        for (int ks = 0; ks < 2; ++ks) {
            MF(a0[ks], b0[ks], acc[mt0 + 0][ntb + 0]);
            MF(a0[ks], b1[ks], acc[mt0 + 0][ntb + 1]);
            MF(a1[ks], b0[ks], acc[mt0 + 1][ntb + 0]);
            MF(a1[ks], b1[ks], acc[mt0 + 1][ntb + 1]);
            MF(a2[ks], b0[ks], acc[mt0 + 2][ntb + 0]);
            MF(a2[ks], b1[ks], acc[mt0 + 2][ntb + 1]);
            MF(a3[ks], b0[ks], acc[mt0 + 3][ntb + 0]);
            MF(a3[ks], b1[ks], acc[mt0 + 3][ntb + 1]);
        }
        __builtin_amdgcn_s_setprio(0);
        __builtin_amdgcn_s_barrier();
    }

    // ---- Epilogue: exp + mask + quad-reduce + LDS reduce + P store ----
    __syncthreads();                     // vmcnt==0 here; fence LDS reuse
    float* red = (float*)&As0[0];        // [4 wn][256 rows], 4 KB

    const int ord  = order_p[0];
    const int qIdx = colb / (KQ / BN);   // 32 col-blocks per queue
    const bool isOrd = (qIdx == ord);
    const int kbase = n0 - qIdx * KQ;

    int qtv[4] = {0, 0, 0, 0};
    if (isOrd) {
        #pragma unroll
        for (int nt = 0; nt < 4; nt++)
            qtv[nt] = q_targets[ord * KQ + kbase + wn * 64 + nt * 16 + l15];
    }

    #pragma unroll
    for (int mt = 0; mt < 8; mt++) {
        int rowl = wm * 128 + mt * 16 + quad * 4;       // local row base
        int tg[4] = {0, 0, 0, 0};
        if (isOrd) {
            #pragma unroll
            for (int reg = 0; reg < 4; reg++) tg[reg] = targets[m0 + rowl + reg];
        }
        #pragma unroll
        for (int reg = 0; reg < 4; reg++) {
            float s = 0.f;
            #pragma unroll
            for (int nt = 0; nt < 4; nt++) {
                float v256 = acc[mt][nt][reg];          // 256 * sim
                float e = __expf(v256 * 0.015625f - 4.0f); // exp(4*sim-4)
                if (isOrd && tg[reg] == qtv[nt]) e = 0.f;
                s += e;
            }
            s += __shfl_xor(s, 1, 64);
            s += __shfl_xor(s, 2, 64);
            s += __shfl_xor(s, 4, 64);
            s += __shfl_xor(s, 8, 64);
            if (l15 == 0)
                red[wn * 256 + rowl + reg] = s;   // unique slot per wave
        }
    }
    __syncthreads();
    if (tid < 256)
        P[(size_t)colb * N_ROWS + m0 + tid] =
            red[tid] + red[256 + tid] + red[512 + tid] + red[768 + tid];
}

// ---------------------------------------------------------------------------
// Kernel 3: per-row total = sum over 96 partials (coalesced), count via
// per-wave ballot histogram, then accumulate mean(log(total/cnt)) into
// out (zeroed by norm_cast earlier in the stream).
// ---------------------------------------------------------------------------
__global__ __launch_bounds__(256) void reduce_kernel(
    const float* __restrict__ P,
    const int* __restrict__ targets,
    const int* __restrict__ q_targets,
    const int* __restrict__ order_p,
    float* __restrict__ out) {
    __shared__ int hist[NCLASS];
    __shared__ float partial[4];
    int tid = threadIdx.x;
    int wave = tid >> 6, lane = tid & 63;
    if (tid < NCLASS) hist[tid] = 0;
    __syncthreads();
    int ord = order_p[0];

    int local[NCLASS];
    #pragma unroll
    for (int c = 0; c < NCLASS; c++) local[c] = 0;
    for (int i = tid; i < KQ; i += 256) {           // 32 iterations
        int v = q_targets[ord * KQ + i];
        #pragma unroll
        for (int c = 0; c < NCLASS; c++)
            local[c] += __popcll(__ballot(v == c)); // wave-uniform count
    }
    if (lane == 0) {
        #pragma unroll
        for (int c = 0; c < NCLASS; c++)
            atomicAdd(&hist[c], local[c]);
    }
    __syncthreads();

    int r = blockIdx.x * 256 + tid;      // 8 blocks x 256 = 2048 rows
    float total = 0.f;
    #pragma unroll 8
    for (int nb = 0; nb < NBLKP; nb++)
        total += P[(size_t)nb * N_ROWS + r];   // coalesced across threads
    float cnt = (float)(QN * KQ - hist[targets[r]]);
    float v = logf(total / cnt);

    #pragma unroll
    for (int off = 1; off < 64; off <<= 1)
        v += __shfl_xor(v, off, 64);
    if (lane == 0) partial[wave] = v;
    __syncthreads();
    if (tid == 0)
        atomicAdd(out, (partial[0] + partial[1] + partial[2] + partial[3])
                       * (1.0f / (float)N_ROWS));
}

// ---------------------------------------------------------------------------
extern "C" void kernel_launch(void* const* d_in, const int* in_sizes, int n_in,
                              void* d_out, int out_size, void* d_ws, size_t ws_size,
                              hipStream_t stream) {
    const float* x         = (const float*)d_in[0];
    const float* q         = (const float*)d_in[1];
    const int*   targets   = (const int*)d_in[2];
    const int*   q_targets = (const int*)d_in[3];
    const int*   order     = (const int*)d_in[4];
    float* out = (float*)d_out;

    // Workspace: P (96*2048 f32 = 768 KB) | Xb (1 MB fp8) | Qb (12 MB fp8)
    char* ws = (char*)d_ws;
    float* P = (float*)ws;
    unsigned char* Xb = (unsigned char*)(ws + (size_t)NBLKP * N_ROWS * 4);
    unsigned char* Qb = Xb + (size_t)N_ROWS * DIM;

    norm_cast_kernel<<<(N_ROWS + NCOL) / 4, 256, 0, stream>>>(x, q, Xb, Qb, out);

    gemm_epilogue_kernel<<<NBLKP * (N_ROWS / BM), 512, 0, stream>>>(
        Xb, Qb, targets, q_targets, order, P);

    reduce_kernel<<<N_ROWS / 256, 256, 0, stream>>>(P, targets, q_targets, order, out);
}

// Round 8
// 170.071 us; speedup vs baseline: 1.1259x; 1.0613x over previous
//
#include <hip/hip_runtime.h>
#include <cstdint>
#include <cstddef>

// Problem constants (fixed by setup_inputs)
#define N_ROWS 2048
#define DIM    512
#define QN     3
#define KQ     8192
#define NCOL   (QN * KQ)   // 24576
#define NCLASS 16

// half-tile-phase 256x256 fp8 GEMM geometry
#define BM 256
#define BN 256
#define BKT 64              // K-tile depth (fp8: 64 B row slabs)
#define NT  (DIM / BKT)     // 8 K-tiles
#define NBLKP (NCOL / BN)   // 96 column blocks

typedef __attribute__((ext_vector_type(4))) float f32x4;

// ---------------------------------------------------------------------------
// Kernel 1: L2-normalize rows of x and q_data, scale by 16, cast to fp8
// e4m3 (OCP). One wave per row; 4 rows per 256-thread block.
// GLOBAL HALF-SWAP keyed on row bit2 (64-B slabs): rows with bit2 set
// store each 16-B chunk's two 8-B halves swapped, baking the LDS swizzle's
// half-bit into global memory so global_load_lds (which cannot permute
// within a 16-B load) still works.  Zeroes out[0].
// ---------------------------------------------------------------------------
__global__ __launch_bounds__(256) void norm_cast_kernel(
    const float* __restrict__ x, const float* __restrict__ q,
    unsigned char* __restrict__ xb, unsigned char* __restrict__ qb,
    float* __restrict__ out) {
    if (blockIdx.x == 0 && threadIdx.x == 0) out[0] = 0.f;
    int row = blockIdx.x * 4 + (threadIdx.x >> 6);
    int lane = threadIdx.x & 63;
    const float* src;
    unsigned char* dst;
    if (row < N_ROWS) {
        src = x + (size_t)row * DIM;
        dst = xb + (size_t)row * DIM;
    } else {
        src = q + (size_t)(row - N_ROWS) * DIM;
        dst = qb + (size_t)(row - N_ROWS) * DIM;
    }
    float4 v0 = ((const float4*)src)[lane * 2];
    float4 v1 = ((const float4*)src)[lane * 2 + 1];
    float ss = v0.x*v0.x + v0.y*v0.y + v0.z*v0.z + v0.w*v0.w
             + v1.x*v1.x + v1.y*v1.y + v1.z*v1.z + v1.w*v1.w;
    #pragma unroll
    for (int off = 1; off < 64; off <<= 1)
        ss += __shfl_xor(ss, off, 64);
    float inv = 16.0f / fmaxf(sqrtf(ss), 1e-12f);
    int w0 = __builtin_amdgcn_cvt_pk_fp8_f32(v0.x * inv, v0.y * inv, 0,  false);
    w0     = __builtin_amdgcn_cvt_pk_fp8_f32(v0.z * inv, v0.w * inv, w0, true);
    int w1 = __builtin_amdgcn_cvt_pk_fp8_f32(v1.x * inv, v1.y * inv, 0,  false);
    w1     = __builtin_amdgcn_cvt_pk_fp8_f32(v1.z * inv, v1.w * inv, w1, true);
    uint2 o; o.x = (unsigned)w0; o.y = (unsigned)w1;
    // half-swap bake: lane's 8 B go to (lane*8) ^ (row.bit2 * 8)
    int r2 = (row >> 2) & 1;
    *(uint2*)(dst + ((lane * 8) ^ (r2 << 3))) = o;
}

// ---------------------------------------------------------------------------
// Kernel 2: fp8 MFMA GEMM (M=2048, N=24576, K=512), result = 256*sim.
// ROUND-13 (round-12 post-mortem: 75us, MfmaUtil 26%, conflicts 3.1M):
// quadrant phases re-read shared operands (q0/q1 share A rows, q0/q2
// share B rows) -> 48 b64 reads/tile where 24 are unique, 8 barriers for
// 16 MFMA each.  RESTRUCTURED to 2 half-tile phases per K-tile:
//   s0: read A rows 0-3 + ALL B (16 b64), stage 2, barrier, 32 MFMA
//       (acc rows 0-3 x 4 cols), barrier.
//   s1: read A rows 4-7 (8 b64; B persists in 16 VGPRs), stage 2,
//       [vmcnt(3) tile-boundary], barrier, 32 MFMA (rows 4-7), barrier.
// 24 reads + 4 barriers per tile (was 48 + 8); MFMA per phase doubles to
// ~1240 cy/SIMD vs ~constant phase overhead.  16 phases EXPLICITLY macro-
// expanded (no loop): guaranteed constant folding of buffers/stages/waits.
// Counted-vmcnt chain (re-derived, every s1): vmcnt(3) leaves 3 half-tiles
// in flight, next tile complete; vmcnt(0) only at phase 13 (tile7 drain).
// sched_barrier(0) pins reads-before-stages (read-wins-DMA ordering).
// Kept from round 12: alias-split As0/As1/Bs0/Bs1; bank-complete swizzle
//   r*64 + ((slot ^ (2*r.b1+r.b3))<<4) + ((half ^ r.b2)<<3) + (k&7)
// (each quad's 16 b64 lanes cover all 32 banks exactly once); XCD decode.
// ---------------------------------------------------------------------------
#define MF(A_, B_, C_) C_ = __builtin_amdgcn_mfma_f32_16x16x32_fp8_fp8(A_, B_, C_, 0, 0, 0)

#define STAGE(h_) do {                                                          \
    const int t_ = (h_) >> 2, ht_ = (h_) & 3;                                   \
    const int chunk_ = (ht_ & 1) * 8 + wave;   /* 8 KB half: 8 chunks */        \
    const int R_ = chunk_ * 16 + stR;          /* tile row 0..255 */            \
    const int k0_ = t_ * BKT;                                                   \
    if (ht_ < 2) {                                                              \
        unsigned char* d_ = ((t_ & 1) ? As1 : As0) + chunk_ * 1024 + lane * 16; \
        __builtin_amdgcn_global_load_lds(                                       \
            (const __attribute__((address_space(1))) unsigned int*)             \
                (Xb + (size_t)(m0 + R_) * DIM + k0_ + stC),                     \
            (__attribute__((address_space(3))) unsigned int*)d_, 16, 0, 0);     \
    } else {                                                                    \
        unsigned char* d_ = ((t_ & 1) ? Bs1 : Bs0) + chunk_ * 1024 + lane * 16; \
        __builtin_amdgcn_global_load_lds(                                       \
            (const __attribute__((address_space(1))) unsigned int*)             \
                (Qb + (size_t)(n0 + R_) * DIM + k0_ + stC),                     \
            (__attribute__((address_space(3))) unsigned int*)d_, 16, 0, 0);     \
    }                                                                           \
} while (0)

// Read A fragment rows MT0..MT0+3 (8 x b64) from buffer AB.
#define RD_A(AB, MT0) do {                                                      \
    const unsigned char* p_;                                                    \
    p_ = (AB) + (wm * 128 + ((MT0) + 0) * 16 + l15) * BKT;                      \
    a0[0] = *(const long*)(p_ + sw0); a0[1] = *(const long*)(p_ + sw1);         \
    p_ = (AB) + (wm * 128 + ((MT0) + 1) * 16 + l15) * BKT;                      \
    a1[0] = *(const long*)(p_ + sw0); a1[1] = *(const long*)(p_ + sw1);         \
    p_ = (AB) + (wm * 128 + ((MT0) + 2) * 16 + l15) * BKT;                      \
    a2[0] = *(const long*)(p_ + sw0); a2[1] = *(const long*)(p_ + sw1);         \
    p_ = (AB) + (wm * 128 + ((MT0) + 3) * 16 + l15) * BKT;                      \
    a3[0] = *(const long*)(p_ + sw0); a3[1] = *(const long*)(p_ + sw1);         \
} while (0)

// Read ALL B fragment rows (8 x b64) into the persistent B0..B3.
#define RD_B(BB) do {                                                           \
    const unsigned char* p_;                                                    \
    p_ = (BB) + (wn * 64 +  0 + l15) * BKT;                                     \
    B0[0] = *(const long*)(p_ + sw0); B0[1] = *(const long*)(p_ + sw1);         \
    p_ = (BB) + (wn * 64 + 16 + l15) * BKT;                                     \
    B1[0] = *(const long*)(p_ + sw0); B1[1] = *(const long*)(p_ + sw1);         \
    p_ = (BB) + (wn * 64 + 32 + l15) * BKT;                                     \
    B2[0] = *(const long*)(p_ + sw0); B2[1] = *(const long*)(p_ + sw1);         \
    p_ = (BB) + (wn * 64 + 48 + l15) * BKT;                                     \
    B3[0] = *(const long*)(p_ + sw0); B3[1] = *(const long*)(p_ + sw1);         \
} while (0)

// 16 MFMAs at k-slab KS for acc rows MT0..MT0+3 (all independent).
#define MFMA16(KS, MT0)                                                         \
    MF(a0[KS], B0[KS], acc[(MT0)+0][0]); MF(a0[KS], B1[KS], acc[(MT0)+0][1]);   \
    MF(a0[KS], B2[KS], acc[(MT0)+0][2]); MF(a0[KS], B3[KS], acc[(MT0)+0][3]);   \
    MF(a1[KS], B0[KS], acc[(MT0)+1][0]); MF(a1[KS], B1[KS], acc[(MT0)+1][1]);   \
    MF(a1[KS], B2[KS], acc[(MT0)+1][2]); MF(a1[KS], B3[KS], acc[(MT0)+1][3]);   \
    MF(a2[KS], B0[KS], acc[(MT0)+2][0]); MF(a2[KS], B1[KS], acc[(MT0)+2][1]);   \
    MF(a2[KS], B2[KS], acc[(MT0)+2][2]); MF(a2[KS], B3[KS], acc[(MT0)+2][3]);   \
    MF(a3[KS], B0[KS], acc[(MT0)+3][0]); MF(a3[KS], B1[KS], acc[(MT0)+3][1]);   \
    MF(a3[KS], B2[KS], acc[(MT0)+3][2]); MF(a3[KS], B3[KS], acc[(MT0)+3][3]);

#define VM3 do { asm volatile("s_waitcnt vmcnt(3)" ::: "memory");               \
                 __builtin_amdgcn_sched_barrier(0); } while (0)
#define VM0 do { asm volatile("s_waitcnt vmcnt(0)" ::: "memory");               \
                 __builtin_amdgcn_sched_barrier(0); } while (0)
#define NOSTG ((void)0)

// s0 phase: A rows 0-3 + all B; 32 MFMA on acc rows 0-3.  No wait.
#define PH_S0(AB, BB, S1_, S2_) do {                                            \
    long a0[2], a1[2], a2[2], a3[2];                                            \
    RD_A(AB, 0); RD_B(BB);                                                      \
    __builtin_amdgcn_sched_barrier(0);                                          \
    S1_; S2_;                                                                   \
    __builtin_amdgcn_s_barrier();                                               \
    __builtin_amdgcn_s_setprio(1);                                              \
    MFMA16(0, 0) MFMA16(1, 0)                                                   \
    __builtin_amdgcn_s_setprio(0);                                              \
    __builtin_amdgcn_s_barrier();                                               \
} while (0)

// s1 phase: A rows 4-7 (B persists in regs); wait; 32 MFMA on rows 4-7.
#define PH_S1(AB, S1_, S2_, WAIT_) do {                                         \
    long a0[2], a1[2], a2[2], a3[2];                                            \
    RD_A(AB, 4);                                                                \
    __builtin_amdgcn_sched_barrier(0);                                          \
    S1_; S2_;                                                                   \
    WAIT_;                                                                      \
    __builtin_amdgcn_s_barrier();                                               \
    __builtin_amdgcn_s_setprio(1);                                              \
    MFMA16(0, 4) MFMA16(1, 4)                                                   \
    __builtin_amdgcn_s_setprio(0);                                              \
    __builtin_amdgcn_s_barrier();                                               \
} while (0)

__global__ __launch_bounds__(512) void gemm_epilogue_kernel(
    const unsigned char* __restrict__ Xb,   // [2048][512] fp8 (half-baked)
    const unsigned char* __restrict__ Qb,   // [24576][512] fp8 (half-baked)
    const int* __restrict__ targets,
    const int* __restrict__ q_targets,
    const int* __restrict__ order_p,
    float* __restrict__ P) {                 // [NBLKP][N_ROWS] partial sums

    __shared__ unsigned char As0[BM * BKT];  // 16 KB each, 64 KB total
    __shared__ unsigned char As1[BM * BKT];
    __shared__ unsigned char Bs0[BN * BKT];
    __shared__ unsigned char Bs1[BN * BKT];

    const int tid  = threadIdx.x;
    const int lane = tid & 63;
    const int wave = tid >> 6;               // 0..7
    const int wm = wave >> 2, wn = wave & 3; // 2M x 4N wave grid
    const int quad = lane >> 4;              // 0..3
    const int l15  = lane & 15;
    const int r2l  = (l15 >> 2) & 1;         // row bit2 (half-XOR key)
    const int skey = ((l15 >> 1) & 1) * 2 + ((l15 >> 3) & 1); // slot key (b1,b3)

    // XCD-aware decode: 768 blocks, 8 rowb x 96 colb.
    const int b    = blockIdx.x;             // 0..767
    const int xcd  = b & 7;
    const int g    = b >> 3;                 // 0..95
    const int colb = (g >> 3) * 8 + xcd;     // 0..95
    const int rowb = g & 7;                  // 0..7
    const int m0 = rowb * BM;
    const int n0 = colb * BN;

    f32x4 acc[8][4];
    #pragma unroll
    for (int i = 0; i < 8; i++)
        #pragma unroll
        for (int j = 0; j < 4; j++)
            acc[i][j] = (f32x4){0.f, 0.f, 0.f, 0.f};

    // Staging: 1-KB chunk = 16 rows x 64 B. Lane l -> row chunk*16+(l>>2),
    // global 16-B seg (l&3) ^ slot_key(row) (inverse of read-side slot
    // XOR; the half-bit lives in the global layout).
    const int stR = lane >> 2;                       // 0..15
    const int stC = ((lane & 3) ^ (((stR >> 1) & 1) * 2 + ((stR >> 3) & 1))) * 16;

    // Loop-invariant fragment-read offsets (ks = 0 and 32):
    //   logical slot s = (ks>>4) + (quad>>1), half h = quad&1
    //   phys = ((s ^ skey)<<4) + ((h ^ b2)<<3)
    const int swh = ((quad & 1) ^ r2l) << 3;
    const int sw0 = ((((quad >> 1)    ) ^ skey) << 4) + swh; // ks=0
    const int sw1 = ((((quad >> 1) + 2) ^ skey) << 4) + swh; // ks=32

    // Persistent B fragments (16 VGPRs), live s0 -> s1 within each tile.
    long B0[2], B1[2], B2[2], B3[2];

    // ---- Prologue: stage 7 half-tiles (tile0 full + tile1 A0,A1,B0) ----
    #pragma unroll
    for (int h = 0; h < 7; ++h) STAGE(h);
    asm volatile("s_waitcnt vmcnt(3)" ::: "memory");   // tile 0 landed
    __builtin_amdgcn_sched_barrier(0);
    __builtin_amdgcn_s_barrier();

    // ---- Main: 16 explicit phases (8 tiles x {s0, s1}) ----
    PH_S0(As0, Bs0, STAGE(7),  STAGE(8));           // t0.s0
    PH_S1(As0,      STAGE(9),  STAGE(10), VM3);     // t0.s1 -> tile1 ready
    PH_S0(As1, Bs1, STAGE(11), STAGE(12));          // t1.s0
    PH_S1(As1,      STAGE(13), STAGE(14), VM3);     // t1.s1 -> tile2 ready
    PH_S0(As0, Bs0, STAGE(15), STAGE(16));          // t2.s0
    PH_S1(As0,      STAGE(17), STAGE(18), VM3);     // t2.s1 -> tile3 ready
    PH_S0(As1, Bs1, STAGE(19), STAGE(20));          // t3.s0
    PH_S1(As1,      STAGE(21), STAGE(22), VM3);     // t3.s1 -> tile4 ready
    PH_S0(As0, Bs0, STAGE(23), STAGE(24));          // t4.s0
    PH_S1(As0,      STAGE(25), STAGE(26), VM3);     // t4.s1 -> tile5 ready
    PH_S0(As1, Bs1, STAGE(27), STAGE(28));          // t5.s0
    PH_S1(As1,      STAGE(29), STAGE(30), VM3);     // t5.s1 -> tile6 ready
    PH_S0(As0, Bs0, STAGE(31), NOSTG);              // t6.s0
    PH_S1(As0,      NOSTG, NOSTG, VM0);             // t6.s1 -> tile7 ready
    PH_S0(As1, Bs1, NOSTG, NOSTG);                  // t7.s0
    PH_S1(As1,      NOSTG, NOSTG, NOSTG);           // t7.s1

    // ---- Epilogue: exp + mask + quad-reduce + LDS reduce + P store ----
    __syncthreads();                     // vmcnt==0 here; fence LDS reuse
    float* red = (float*)&As0[0];        // [4 wn][256 rows], 4 KB

    const int ord  = order_p[0];
    const int qIdx = colb / (KQ / BN);   // 32 col-blocks per queue
    const bool isOrd = (qIdx == ord);
    const int kbase = n0 - qIdx * KQ;

    int qtv[4] = {0, 0, 0, 0};
    if (isOrd) {
        #pragma unroll
        for (int nt = 0; nt < 4; nt++)
            qtv[nt] = q_targets[ord * KQ + kbase + wn * 64 + nt * 16 + l15];
    }

    #pragma unroll
    for (int mt = 0; mt < 8; mt++) {
        int rowl = wm * 128 + mt * 16 + quad * 4;       // local row base
        int tg[4] = {0, 0, 0, 0};
        if (isOrd) {
            #pragma unroll
            for (int reg = 0; reg < 4; reg++) tg[reg] = targets[m0 + rowl + reg];
        }
        #pragma unroll
        for (int reg = 0; reg < 4; reg++) {
            float s = 0.f;
            #pragma unroll
            for (int nt = 0; nt < 4; nt++) {
                float v256 = acc[mt][nt][reg];          // 256 * sim
                float e = __expf(v256 * 0.015625f - 4.0f); // exp(4*sim-4)
                if (isOrd && tg[reg] == qtv[nt]) e = 0.f;
                s += e;
            }
            s += __shfl_xor(s, 1, 64);
            s += __shfl_xor(s, 2, 64);
            s += __shfl_xor(s, 4, 64);
            s += __shfl_xor(s, 8, 64);
            if (l15 == 0)
                red[wn * 256 + rowl + reg] = s;   // unique slot per wave
        }
    }
    __syncthreads();
    if (tid < 256)
        P[(size_t)colb * N_ROWS + m0 + tid] =
            red[tid] + red[256 + tid] + red[512 + tid] + red[768 + tid];
}

// ---------------------------------------------------------------------------
// Kernel 3: per-row total = sum over 96 partials (coalesced), count via
// per-wave ballot histogram, then accumulate mean(log(total/cnt)) into
// out (zeroed by norm_cast earlier in the stream).
// ---------------------------------------------------------------------------
__global__ __launch_bounds__(256) void reduce_kernel(
    const float* __restrict__ P,
    const int* __restrict__ targets,
    const int* __restrict__ q_targets,
    const int* __restrict__ order_p,
    float* __restrict__ out) {
    __shared__ int hist[NCLASS];
    __shared__ float partial[4];
    int tid = threadIdx.x;
    int wave = tid >> 6, lane = tid & 63;
    if (tid < NCLASS) hist[tid] = 0;
    __syncthreads();
    int ord = order_p[0];

    int local[NCLASS];
    #pragma unroll
    for (int c = 0; c < NCLASS; c++) local[c] = 0;
    for (int i = tid; i < KQ; i += 256) {           // 32 iterations
        int v = q_targets[ord * KQ + i];
        #pragma unroll
        for (int c = 0; c < NCLASS; c++)
            local[c] += __popcll(__ballot(v == c)); // wave-uniform count
    }
    if (lane == 0) {
        #pragma unroll
        for (int c = 0; c < NCLASS; c++)
            atomicAdd(&hist[c], local[c]);
    }
    __syncthreads();

    int r = blockIdx.x * 256 + tid;      // 8 blocks x 256 = 2048 rows
    float total = 0.f;
    #pragma unroll 8
    for (int nb = 0; nb < NBLKP; nb++)
        total += P[(size_t)nb * N_ROWS + r];   // coalesced across threads
    float cnt = (float)(QN * KQ - hist[targets[r]]);
    float v = logf(total / cnt);

    #pragma unroll
    for (int off = 1; off < 64; off <<= 1)
        v += __shfl_xor(v, off, 64);
    if (lane == 0) partial[wave] = v;
    __syncthreads();
    if (tid == 0)
        atomicAdd(out, (partial[0] + partial[1] + partial[2] + partial[3])
                       * (1.0f / (float)N_ROWS));
}

// ---------------------------------------------------------------------------
extern "C" void kernel_launch(void* const* d_in, const int* in_sizes, int n_in,
                              void* d_out, int out_size, void* d_ws, size_t ws_size,
                              hipStream_t stream) {
    const float* x         = (const float*)d_in[0];
    const float* q         = (const float*)d_in[1];
    const int*   targets   = (const int*)d_in[2];
    const int*   q_targets = (const int*)d_in[3];
    const int*   order     = (const int*)d_in[4];
    float* out = (float*)d_out;

    // Workspace: P (96*2048 f32 = 768 KB) | Xb (1 MB fp8) | Qb (12 MB fp8)
    char* ws = (char*)d_ws;
    float* P = (float*)ws;
    unsigned char* Xb = (unsigned char*)(ws + (size_t)NBLKP * N_ROWS * 4);
    unsigned char* Qb = Xb + (size_t)N_ROWS * DIM;

    norm_cast_kernel<<<(N_ROWS + NCOL) / 4, 256, 0, stream>>>(x, q, Xb, Qb, out);

    gemm_epilogue_kernel<<<NBLKP * (N_ROWS / BM), 512, 0, stream>>>(
        Xb, Qb, targets, q_targets, order, P);

    reduce_kernel<<<N_ROWS / 256, 256, 0, stream>>>(P, targets, q_targets, order, out);
}